// Round 5
// baseline (725.863 us; speedup 1.0000x reference)
//
#include <hip/hip_runtime.h>
#include <stdint.h>

typedef unsigned short u16;
typedef __attribute__((ext_vector_type(8))) short short8;
typedef __attribute__((ext_vector_type(4))) float f32x4;

static __device__ __forceinline__ u16 f2bf(float f){
  unsigned int x = __float_as_uint(f);
  unsigned int r = (x + 0x7FFFu + ((x >> 16) & 1u)) >> 16;
  return (u16)r;
}
static __device__ __forceinline__ float bf2f(u16 u){
  return __uint_as_float(((unsigned int)u) << 16);
}

// ---------------- fused prep: convert 7 f32 arrays -> bf16 in one launch ----------------
// segments (f32 elems): x 1048576 | inp_w 393216 | outp_w 393216 | m_in 4718592 |
//                       m_out 2359296 | f1 9437184 | f2 9437184   total 27787264
__global__ __launch_bounds__(256) void prep_cvt(
    const float* __restrict__ s0, const float* __restrict__ s1,
    const float* __restrict__ s2, const float* __restrict__ s3,
    const float* __restrict__ s4, const float* __restrict__ s5,
    const float* __restrict__ s6,
    u16* __restrict__ d0, u16* __restrict__ d1, u16* __restrict__ d2,
    u16* __restrict__ d3, u16* __restrict__ d4, u16* __restrict__ d5,
    u16* __restrict__ d6){
  size_t i = ((size_t)blockIdx.x * 256 + threadIdx.x) * 4;
  const float* src; u16* dst; size_t base;
  if      (i <  1048576){ src = s0; dst = d0; base = 0; }
  else if (i <  1441792){ src = s1; dst = d1; base = 1048576; }
  else if (i <  1835008){ src = s2; dst = d2; base = 1441792; }
  else if (i <  6553600){ src = s3; dst = d3; base = 1835008; }
  else if (i <  8912896){ src = s4; dst = d4; base = 6553600; }
  else if (i < 18350080){ src = s5; dst = d5; base = 8912896; }
  else                  { src = s6; dst = d6; base = 18350080; }
  size_t o = i - base;
  float4 v = *reinterpret_cast<const float4*>(src + o);
  union { u16 u[4]; unsigned long long ll; } t;
  t.u[0] = f2bf(v.x); t.u[1] = f2bf(v.y); t.u[2] = f2bf(v.z); t.u[3] = f2bf(v.w);
  *reinterpret_cast<unsigned long long*>(dst + o) = t.ll;
}

// ---------------- build combined [W_delta ; xproj_BC ; pad] (896 x 768) bf16 per layer ----
__global__ __launch_bounds__(256) void build_dbc(const float* __restrict__ dt_w,
                                                 const float* __restrict__ xproj_w,
                                                 u16* __restrict__ out){
  const int total = 4 * 896 * 768;
  for (int idx = blockIdx.x * 256 + threadIdx.x; idx < total; idx += gridDim.x * 256){
    int l = idx / (896 * 768);
    int rem = idx - l * 896 * 768;
    int row = rem / 768;
    int k = rem - row * 768;
    float v = 0.f;
    if (row < 768){
      const float* dtr = dt_w + ((size_t)l * 768 + row) * 48;
      const float* xp  = xproj_w + (size_t)l * 80 * 768 + k;
      #pragma unroll 8
      for (int j = 0; j < 48; j++) v += dtr[j] * xp[(size_t)j * 768];
    } else if (row < 800){
      v = xproj_w[(size_t)l * 80 * 768 + (size_t)(48 + row - 768) * 768 + k];
    }
    out[idx] = f2bf(v);
  }
}

// ---------------- fused LayerNorm -> xln(f32) + RMSNorm(ln) -> bf16 ----------------
__global__ __launch_bounds__(256) void ln_rms_kernel(const float* __restrict__ in,
                                                     const float* __restrict__ w,
                                                     const float* __restrict__ b,
                                                     const float* __restrict__ rw,
                                                     float* __restrict__ xln,
                                                     u16* __restrict__ outB){
  int row = blockIdx.x;
  const float* x = in + (size_t)row * 768;
  int t = threadIdx.x;
  float v0 = x[t], v1 = x[t + 256], v2 = x[t + 512];
  float s = v0 + v1 + v2;
  float s2 = v0 * v0 + v1 * v1 + v2 * v2;
  #pragma unroll
  for (int off = 1; off < 64; off <<= 1){ s += __shfl_xor(s, off); s2 += __shfl_xor(s2, off); }
  __shared__ float red[8];
  int wid = t >> 6, lane = t & 63;
  if (lane == 0){ red[wid] = s; red[4 + wid] = s2; }
  __syncthreads();
  s = red[0] + red[1] + red[2] + red[3];
  s2 = red[4] + red[5] + red[6] + red[7];
  float mean = s * (1.f / 768.f);
  float var = s2 * (1.f / 768.f) - mean * mean;
  float rstd = rsqrtf(var + 1e-5f);
  float o0 = (v0 - mean) * rstd * w[t] + b[t];
  float o1 = (v1 - mean) * rstd * w[t + 256] + b[t + 256];
  float o2 = (v2 - mean) * rstd * w[t + 512] + b[t + 512];
  xln[(size_t)row * 768 + t]       = o0;
  xln[(size_t)row * 768 + t + 256] = o1;
  xln[(size_t)row * 768 + t + 512] = o2;
  float q = o0 * o0 + o1 * o1 + o2 * o2;
  #pragma unroll
  for (int off = 1; off < 64; off <<= 1){ q += __shfl_xor(q, off); }
  __syncthreads();
  if (lane == 0) red[wid] = q;
  __syncthreads();
  q = red[0] + red[1] + red[2] + red[3];
  float rs = rsqrtf(q * (1.f / 768.f) + 1e-5f);
  outB[(size_t)row * 768 + t]       = f2bf(o0 * rs * rw[t]);
  outB[(size_t)row * 768 + t + 256] = f2bf(o1 * rs * rw[t + 256]);
  outB[(size_t)row * 768 + t + 512] = f2bf(o2 * rs * rw[t + 512]);
}

// ---------------- LayerNorm (row=768) -> bf16 only ----------------
__global__ __launch_bounds__(256) void ln_kernel(const float* __restrict__ in,
                                                 const float* __restrict__ w,
                                                 const float* __restrict__ b,
                                                 u16* __restrict__ outB){
  int row = blockIdx.x;
  const float* x = in + (size_t)row * 768;
  int t = threadIdx.x;
  float v0 = x[t], v1 = x[t + 256], v2 = x[t + 512];
  float s = v0 + v1 + v2;
  float s2 = v0 * v0 + v1 * v1 + v2 * v2;
  #pragma unroll
  for (int off = 1; off < 64; off <<= 1){ s += __shfl_xor(s, off); s2 += __shfl_xor(s2, off); }
  __shared__ float red[8];
  int wid = t >> 6, lane = t & 63;
  if (lane == 0){ red[wid] = s; red[4 + wid] = s2; }
  __syncthreads();
  s = red[0] + red[1] + red[2] + red[3];
  s2 = red[4] + red[5] + red[6] + red[7];
  float mean = s * (1.f / 768.f);
  float var = s2 * (1.f / 768.f) - mean * mean;
  float rstd = rsqrtf(var + 1e-5f);
  #pragma unroll
  for (int j = 0; j < 3; j++){
    int e = t + j * 256;
    float v = (j == 0) ? v0 : (j == 1) ? v1 : v2;
    outB[(size_t)row * 768 + e] = f2bf((v - mean) * rstd * w[e] + b[e]);
  }
}

// ---------------- depthwise causal conv K=4 + bias + SiLU -> bf16 ----------------
__global__ __launch_bounds__(256) void conv_silu(const float* __restrict__ xz,
                                                 const float* __restrict__ cw,
                                                 const float* __restrict__ cb,
                                                 u16* __restrict__ xi){
  int row = blockIdx.x;            // 0..2047
  int b = row >> 10, l = row & 1023;
  for (int e = threadIdx.x; e < 768; e += 256){
    const float* w = cw + (size_t)e * 4;
    float acc = cb[e];
    #pragma unroll
    for (int k = 0; k < 4; k++){
      int ls = l - 3 + k;
      if (ls >= 0) acc += w[k] * xz[((size_t)((b << 10) + ls)) * 1536 + e];
    }
    float sv = acc / (1.f + __expf(-acc));
    xi[(size_t)row * 768 + e] = f2bf(sv);
  }
}

// ---------------- selective scan: pass 1 (chunk summaries) ----------------
__global__ __launch_bounds__(256) void scan_pass1(const float* __restrict__ delta,
                                                  const u16* __restrict__ xi,
                                                  const float* __restrict__ bc,
                                                  const float* __restrict__ A_log,
                                                  float* __restrict__ asum,
                                                  float* __restrict__ bsum){
  int bid = blockIdx.x;
  int eg = bid % 3; int c = (bid / 3) & 63; int b = bid / 192;
  int e = eg * 256 + threadIdx.x;
  float A[16], a[16], s[16];
  const float* al = A_log + (size_t)e * 16;
  #pragma unroll
  for (int n = 0; n < 16; n++){ A[n] = -__expf(al[n]); a[n] = 1.f; s[n] = 0.f; }
  for (int ll = 0; ll < 16; ll++){
    int row = b * 1024 + c * 16 + ll;
    float dlt = delta[(size_t)row * 768 + e];
    float xiv = bf2f(xi[(size_t)row * 768 + e]);
    float du = dlt * xiv;
    const float* bm = bc + (size_t)row * 32;
    #pragma unroll
    for (int n = 0; n < 16; n++){
      float dA = __expf(dlt * A[n]);
      s[n] = dA * s[n] + du * bm[n];
      a[n] *= dA;
    }
  }
  size_t base = (((size_t)(b * 64 + c) * 768) + e) * 16;
  #pragma unroll
  for (int n = 0; n < 16; n++){ asum[base + n] = a[n]; bsum[base + n] = s[n]; }
}

// ---------------- scan pass 2: combine 64 chunk summaries ----------------
__global__ __launch_bounds__(256) void scan_pass2(const float* __restrict__ asum,
                                                  const float* __restrict__ bsum,
                                                  float* __restrict__ h0){
  int idx = blockIdx.x * 256 + threadIdx.x;  // b*12288 + e*16 + n
  int b = idx / 12288;
  int en = idx - b * 12288;
  float h = 0.f;
  for (int c = 0; c < 64; c++){
    size_t i = ((size_t)(b * 64 + c) * 12288) + en;
    h0[i] = h;
    h = asum[i] * h + bsum[i];
  }
}

// ---------------- scan pass 3: rescan with init state + y epilogue ----------------
__global__ __launch_bounds__(256) void scan_pass3(const float* __restrict__ delta,
                                                  const u16* __restrict__ xi,
                                                  const float* __restrict__ bc,
                                                  const float* __restrict__ A_log,
                                                  const float* __restrict__ h0,
                                                  const float* __restrict__ Dp,
                                                  const float* __restrict__ xz,
                                                  u16* __restrict__ y){
  int bid = blockIdx.x;
  int eg = bid % 3; int c = (bid / 3) & 63; int b = bid / 192;
  int e = eg * 256 + threadIdx.x;
  float A[16], s[16];
  const float* al = A_log + (size_t)e * 16;
  #pragma unroll
  for (int n = 0; n < 16; n++) A[n] = -__expf(al[n]);
  size_t base = (((size_t)(b * 64 + c) * 768) + e) * 16;
  #pragma unroll
  for (int n = 0; n < 16; n++) s[n] = h0[base + n];
  float dp = Dp[e];
  for (int ll = 0; ll < 16; ll++){
    int row = b * 1024 + c * 16 + ll;
    float dlt = delta[(size_t)row * 768 + e];
    float xiv = bf2f(xi[(size_t)row * 768 + e]);
    float du = dlt * xiv;
    const float* bm = bc + (size_t)row * 32;
    const float* cm = bm + 16;
    float acc = 0.f;
    #pragma unroll
    for (int n = 0; n < 16; n++){
      float dA = __expf(dlt * A[n]);
      s[n] = dA * s[n] + du * bm[n];
      acc += s[n] * cm[n];
    }
    float yv = acc + dp * xiv;
    float z = xz[(size_t)row * 1536 + 768 + e];
    yv *= z / (1.f + __expf(-z));
    y[(size_t)row * 768 + e] = f2bf(yv);
  }
}

// ---------------- bf16 MFMA GEMM, 128x64 tile, BK=64, 3 LDS bufs, depth-2 --------------
// Wave = 64x32 output (4x2 16x16 frags): 16 MFMA : 12 ds_read_b128 per K-iter.
// Raw s_barrier + counted vmcnt keeps prefetch in flight across barriers.
// Stage is issued AFTER the barrier so 3 buffers suffice (writes to (kt+2)%3 cannot
// collide with iter kt-1 reads, which completed before barrier kt).
// MODE 0: outF = v + bias? + r1? + r2?  (+ optional outB = bf16(result))
// MODE 1: outB = bf16(relu(v + bias))
// MODE 2: col<768 -> dl = softplus(v+dtb); col<800 -> bco = v; else drop
template<int MODE>
__global__ __launch_bounds__(256, 2) void gemm128x64(
    const u16* __restrict__ A, const u16* __restrict__ Bw, int N, int Kd,
    float* __restrict__ outF, u16* __restrict__ outB,
    const float* __restrict__ bias, const float* __restrict__ r1,
    const float* __restrict__ r2,
    float* __restrict__ dl, float* __restrict__ bco, const float* __restrict__ dtb){
  __shared__ u16 sm[3][(128 + 64) * 64];   // 73.7 KB: 3 bufs x {A:128x64, B:64x64}
  const int tid = threadIdx.x;
  const int wid = tid >> 6, lane = tid & 63;
  const int lhi = lane >> 4, llo = lane & 15;
  const int wr = wid >> 1, wc = wid & 1;      // 2x2 wave grid
  // XCD-aware swizzle (gridDim.x == 16 always; nwg % 8 == 0 for all our shapes)
  int nwg = (int)(gridDim.x * gridDim.y);
  int orig = (int)(blockIdx.y * gridDim.x + blockIdx.x);
  int wg = (orig & 7) * (nwg >> 3) + (orig >> 3);
  const int m0 = (wg & 15) * 128, n0 = (wg >> 4) * 64;
  const int nk = Kd >> 6;
  f32x4 acc[4][2] = {};

  auto stage = [&](int buf, int kt){
    const u16* Ab = A + (size_t)m0 * Kd + kt * 64;
    const u16* Bb = Bw + (size_t)n0 * Kd + kt * 64;
    u16* base = &sm[buf][0];
    #pragma unroll
    for (int j = 0; j < 4; j++){           // A: 128 rows x 8 chunks = 1024
      int sl = j * 256 + tid;
      int row = sl >> 3;
      int ch = (sl & 7) ^ (row & 7);
      __builtin_amdgcn_global_load_lds(
          (const __attribute__((address_space(1))) void*)(Ab + (size_t)row * Kd + ch * 8),
          (__attribute__((address_space(3))) void*)(base + sl * 8), 16, 0, 0);
    }
    #pragma unroll
    for (int j = 0; j < 2; j++){           // B: 64 rows x 8 chunks = 512
      int sl = j * 256 + tid;
      int row = sl >> 3;
      int ch = (sl & 7) ^ (row & 7);
      __builtin_amdgcn_global_load_lds(
          (const __attribute__((address_space(1))) void*)(Bb + (size_t)row * Kd + ch * 8),
          (__attribute__((address_space(3))) void*)(base + 128 * 64 + sl * 8), 16, 0, 0);
    }
  };

  stage(0, 0);
  if (nk > 1) stage(1, 1);
  int bsel = 2;                 // next buffer to stage into
  for (int kt = 0; kt < nk; ++kt){
    if (kt + 1 < nk){
      asm volatile("s_waitcnt vmcnt(6)" ::: "memory");  // tile kt landed; kt+1 in flight
    } else {
      asm volatile("s_waitcnt vmcnt(0)" ::: "memory");
    }
    __builtin_amdgcn_s_barrier();
    __builtin_amdgcn_sched_barrier(0);
    if (kt + 2 < nk){
      stage(bsel, kt + 2);
      bsel = (bsel == 2) ? 0 : bsel + 1;
    }
    int cb = kt % 3;
    const u16* Asb = &sm[cb][0];
    const u16* Bsb = &sm[cb][128 * 64];
    short8 af[4][2], bfr[2][2];
    #pragma unroll
    for (int mi = 0; mi < 4; mi++){
      int row = wr * 64 + mi * 16 + llo;
      const u16* rp = Asb + row * 64;
      #pragma unroll
      for (int s2 = 0; s2 < 2; s2++){
        int ch = (s2 * 4 + lhi) ^ (row & 7);
        af[mi][s2] = *(const short8*)(rp + ch * 8);
      }
    }
    #pragma unroll
    for (int ni = 0; ni < 2; ni++){
      int row = wc * 32 + ni * 16 + llo;
      const u16* rp = Bsb + row * 64;
      #pragma unroll
      for (int s2 = 0; s2 < 2; s2++){
        int ch = (s2 * 4 + lhi) ^ (row & 7);
        bfr[ni][s2] = *(const short8*)(rp + ch * 8);
      }
    }
    #pragma unroll
    for (int s2 = 0; s2 < 2; s2++)
      #pragma unroll
      for (int mi = 0; mi < 4; mi++)
        #pragma unroll
        for (int ni = 0; ni < 2; ni++)
          acc[mi][ni] = __builtin_amdgcn_mfma_f32_16x16x32_bf16(
              af[mi][s2], bfr[ni][s2], acc[mi][ni], 0, 0, 0);
  }
  // epilogue
  #pragma unroll
  for (int mi = 0; mi < 4; mi++){
    #pragma unroll
    for (int ni = 0; ni < 2; ni++){
      int r0 = m0 + wr * 64 + mi * 16 + lhi * 4;
      int c = n0 + wc * 32 + ni * 16 + llo;
      #pragma unroll
      for (int r = 0; r < 4; r++){
        int rr = r0 + r;
        float v = acc[mi][ni][r];
        if (MODE == 0){
          size_t idx = (size_t)rr * N + c;
          if (bias) v += bias[c];
          if (r1) v += r1[idx];
          if (r2) v += r2[idx];
          outF[idx] = v;
          if (outB) outB[idx] = f2bf(v);
        } else if (MODE == 1){
          size_t idx = (size_t)rr * N + c;
          v += bias[c];
          outB[idx] = f2bf(v > 0.f ? v : 0.f);
        } else {
          if (c < 768){
            float tv = v + dtb[c];
            dl[(size_t)rr * 768 + c] = (tv > 20.f) ? tv : log1pf(__expf(tv));
          } else if (c < 800){
            bco[(size_t)rr * 32 + (c - 768)] = v;
          }
        }
      }
    }
  }
}

// ------------------------------------------------------------------
extern "C" void kernel_launch(void* const* d_in, const int* in_sizes, int n_in,
                              void* d_out, int out_size, void* d_ws, size_t ws_size,
                              hipStream_t stream){
  (void)in_sizes; (void)n_in; (void)out_size; (void)ws_size;
  const float* x_f       = (const float*)d_in[0];
  const float* in_proj_w = (const float*)d_in[1];
  const float* in_proj_b = (const float*)d_in[2];
  const float* out_proj_w= (const float*)d_in[3];
  const float* out_proj_b= (const float*)d_in[4];
  const float* ln1_w     = (const float*)d_in[5];
  const float* ln1_b     = (const float*)d_in[6];
  const float* ln2_w     = (const float*)d_in[7];
  const float* ln2_b     = (const float*)d_in[8];
  const float* ffn_w1    = (const float*)d_in[9];
  const float* ffn_b1    = (const float*)d_in[10];
  const float* ffn_w2    = (const float*)d_in[11];
  const float* ffn_b2    = (const float*)d_in[12];
  const float* rms_w     = (const float*)d_in[13];
  const float* m_in_w    = (const float*)d_in[14];
  const float* conv_w    = (const float*)d_in[15];
  const float* conv_b    = (const float*)d_in[16];
  const float* xproj_w   = (const float*)d_in[17];
  const float* dt_w      = (const float*)d_in[18];
  const float* dt_b      = (const float*)d_in[19];
  const float* A_log     = (const float*)d_in[20];
  const float* Dp        = (const float*)d_in[21];
  const float* m_out_w   = (const float*)d_in[22];

  char* ws = (char*)d_ws;
  size_t off = 0;
  auto alloc = [&](size_t bytes) -> char* {
    char* p = ws + off;
    off += (bytes + 255) & ~(size_t)255;
    return p;
  };
  u16* wb_inp  = (u16*)alloc((size_t)768 * 512 * 2);
  u16* wb_outp = (u16*)alloc((size_t)512 * 768 * 2);
  u16* wb_min  = (u16*)alloc((size_t)4 * 1536 * 768 * 2);
  u16* wb_mout = (u16*)alloc((size_t)4 * 768 * 768 * 2);
  u16* wb_f1   = (u16*)alloc((size_t)4 * 3072 * 768 * 2);
  u16* wb_f2   = (u16*)alloc((size_t)4 * 768 * 3072 * 2);
  u16* wb_dbc  = (u16*)alloc((size_t)4 * 896 * 768 * 2);
  u16* xbf     = (u16*)alloc((size_t)2048 * 512 * 2);
  float* hA    = (float*)alloc((size_t)2048 * 768 * 4);
  float* hB    = (float*)alloc((size_t)2048 * 768 * 4);
  float* xln   = (float*)alloc((size_t)2048 * 768 * 4);
  u16* xnbf    = (u16*)alloc((size_t)2048 * 768 * 2);
  float* xz    = (float*)alloc((size_t)2048 * 1536 * 4);
  u16* xibf    = (u16*)alloc((size_t)2048 * 768 * 2);
  float* dltb  = (float*)alloc((size_t)2048 * 768 * 4);
  float* bcb   = (float*)alloc((size_t)2048 * 32 * 4);
  float* asum  = (float*)alloc((size_t)2 * 64 * 768 * 16 * 4);
  float* bsum  = (float*)alloc((size_t)2 * 64 * 768 * 16 * 4);
  float* h0    = (float*)alloc((size_t)2 * 64 * 768 * 16 * 4);
  u16* ybf     = (u16*)alloc((size_t)2048 * 768 * 2);
  u16* tbf     = (u16*)alloc((size_t)2048 * 768 * 2);
  u16* f1bf    = (u16*)alloc((size_t)2048 * 3072 * 2);
  u16* hfbf    = (u16*)alloc((size_t)2048 * 768 * 2);

  // one fused weight/input conversion launch (27787264 f32 / 4 / 256 = 27136 blocks)
  prep_cvt<<<27136, 256, 0, stream>>>(x_f, in_proj_w, out_proj_w, m_in_w,
                                      m_out_w, ffn_w1, ffn_w2,
                                      xbf, wb_inp, wb_outp, wb_min,
                                      wb_mout, wb_f1, wb_f2);
  build_dbc<<<2048, 256, 0, stream>>>(dt_w, xproj_w, wb_dbc);

  auto gemm = [&](int mode, const u16* Ain, const u16* Bww, int N, int K,
                  float* oF, u16* oB, const float* bias, const float* rr1,
                  const float* rr2, float* dl, float* bco, const float* dtb){
    dim3 g(16, N / 64), blk(256);
    if (mode == 0)
      gemm128x64<0><<<g, blk, 0, stream>>>(Ain, Bww, N, K, oF, oB, bias, rr1, rr2, dl, bco, dtb);
    else if (mode == 1)
      gemm128x64<1><<<g, blk, 0, stream>>>(Ain, Bww, N, K, oF, oB, bias, rr1, rr2, dl, bco, dtb);
    else
      gemm128x64<2><<<g, blk, 0, stream>>>(Ain, Bww, N, K, oF, oB, bias, rr1, rr2, dl, bco, dtb);
  };

  // h = x @ in_proj_w.T + b
  gemm(0, xbf, wb_inp, 768, 512, hA, nullptr, in_proj_b, nullptr, nullptr,
       nullptr, nullptr, nullptr);

  for (int i = 0; i < 4; i++){
    ln_rms_kernel<<<2048, 256, 0, stream>>>(hA, ln1_w + i * 768, ln1_b + i * 768,
                                            rms_w + i * 768, xln, xnbf);
    gemm(0, xnbf, wb_min + (size_t)i * 1536 * 768, 1536, 768, xz, nullptr,
         nullptr, nullptr, nullptr, nullptr, nullptr, nullptr);
    conv_silu<<<2048, 256, 0, stream>>>(xz, conv_w + (size_t)i * 768 * 4,
                                        conv_b + i * 768, xibf);
    gemm(2, xibf, wb_dbc + (size_t)i * 896 * 768, 896, 768, nullptr, nullptr,
         nullptr, nullptr, nullptr, dltb, bcb, dt_b + i * 768);
    scan_pass1<<<384, 256, 0, stream>>>(dltb, xibf, bcb,
                                        A_log + (size_t)i * 768 * 16, asum, bsum);
    scan_pass2<<<96, 256, 0, stream>>>(asum, bsum, h0);
    scan_pass3<<<384, 256, 0, stream>>>(dltb, xibf, bcb,
                                        A_log + (size_t)i * 768 * 16, h0,
                                        Dp + i * 768, xz, ybf);
    // h_mid = h + ln1(h) + y @ m_out_w.T
    gemm(0, ybf, wb_mout + (size_t)i * 768 * 768, 768, 768, hB, nullptr,
         nullptr, hA, xln, nullptr, nullptr, nullptr);
    ln_kernel<<<2048, 256, 0, stream>>>(hB, ln2_w + i * 768, ln2_b + i * 768, tbf);
    gemm(1, tbf, wb_f1 + (size_t)i * 3072 * 768, 3072, 768, nullptr, f1bf,
         ffn_b1 + i * 3072, nullptr, nullptr, nullptr, nullptr, nullptr);
    // last layer: also emit bf16 of h for out_proj (skips a cvt kernel)
    gemm(0, f1bf, wb_f2 + (size_t)i * 768 * 3072, 768, 3072, hA,
         (i == 3) ? hfbf : nullptr, ffn_b2 + i * 768, hB, nullptr,
         nullptr, nullptr, nullptr);
  }
  gemm(0, hfbf, wb_outp, 512, 768, (float*)d_out, nullptr, out_proj_b,
       nullptr, nullptr, nullptr, nullptr, nullptr);
}

// Round 6
// 716.599 us; speedup vs baseline: 1.0129x; 1.0129x over previous
//
#include <hip/hip_runtime.h>
#include <stdint.h>

typedef unsigned short u16;
typedef __attribute__((ext_vector_type(8))) short short8;
typedef __attribute__((ext_vector_type(4))) float f32x4;

static __device__ __forceinline__ u16 f2bf(float f){
  unsigned int x = __float_as_uint(f);
  unsigned int r = (x + 0x7FFFu + ((x >> 16) & 1u)) >> 16;
  return (u16)r;
}
static __device__ __forceinline__ float bf2f(u16 u){
  return __uint_as_float(((unsigned int)u) << 16);
}

// ---------------- fused prep: convert 7 f32 arrays -> bf16, 2 float4/thread ----------------
// segment boundaries (f32 elems): 1048576 | 1441792 | 1835008 | 6553600 | 8912896 |
// 18350080 | 27787264  (all multiples of 8)
__global__ __launch_bounds__(256) void prep_cvt(
    const float* __restrict__ s0, const float* __restrict__ s1,
    const float* __restrict__ s2, const float* __restrict__ s3,
    const float* __restrict__ s4, const float* __restrict__ s5,
    const float* __restrict__ s6,
    u16* __restrict__ d0, u16* __restrict__ d1, u16* __restrict__ d2,
    u16* __restrict__ d3, u16* __restrict__ d4, u16* __restrict__ d5,
    u16* __restrict__ d6){
  size_t i = ((size_t)blockIdx.x * 256 + threadIdx.x) * 8;
  const float* src; u16* dst; size_t base;
  if      (i <  1048576){ src = s0; dst = d0; base = 0; }
  else if (i <  1441792){ src = s1; dst = d1; base = 1048576; }
  else if (i <  1835008){ src = s2; dst = d2; base = 1441792; }
  else if (i <  6553600){ src = s3; dst = d3; base = 1835008; }
  else if (i <  8912896){ src = s4; dst = d4; base = 6553600; }
  else if (i < 18350080){ src = s5; dst = d5; base = 8912896; }
  else                  { src = s6; dst = d6; base = 18350080; }
  size_t o = i - base;
  #pragma unroll
  for (int p = 0; p < 2; p++){
    float4 v = *reinterpret_cast<const float4*>(src + o + p * 4);
    union { u16 u[4]; unsigned long long ll; } t;
    t.u[0] = f2bf(v.x); t.u[1] = f2bf(v.y); t.u[2] = f2bf(v.z); t.u[3] = f2bf(v.w);
    *reinterpret_cast<unsigned long long*>(dst + o + p * 4) = t.ll;
  }
}

// ---------------- build combined [W_delta ; xproj_BC ; pad] (896 x 768) bf16 per layer ----
__global__ __launch_bounds__(256) void build_dbc(const float* __restrict__ dt_w,
                                                 const float* __restrict__ xproj_w,
                                                 u16* __restrict__ out){
  const int total = 4 * 896 * 768;
  for (int idx = blockIdx.x * 256 + threadIdx.x; idx < total; idx += gridDim.x * 256){
    int l = idx / (896 * 768);
    int rem = idx - l * 896 * 768;
    int row = rem / 768;
    int k = rem - row * 768;
    float v = 0.f;
    if (row < 768){
      const float* dtr = dt_w + ((size_t)l * 768 + row) * 48;
      const float* xp  = xproj_w + (size_t)l * 80 * 768 + k;
      #pragma unroll 8
      for (int j = 0; j < 48; j++) v += dtr[j] * xp[(size_t)j * 768];
    } else if (row < 800){
      v = xproj_w[(size_t)l * 80 * 768 + (size_t)(48 + row - 768) * 768 + k];
    }
    out[idx] = f2bf(v);
  }
}

// ---------------- fused LayerNorm -> xln(f32) + RMSNorm(ln) -> bf16 ----------------
__global__ __launch_bounds__(256) void ln_rms_kernel(const float* __restrict__ in,
                                                     const float* __restrict__ w,
                                                     const float* __restrict__ b,
                                                     const float* __restrict__ rw,
                                                     float* __restrict__ xln,
                                                     u16* __restrict__ outB){
  int row = blockIdx.x;
  const float* x = in + (size_t)row * 768;
  int t = threadIdx.x;
  float v0 = x[t], v1 = x[t + 256], v2 = x[t + 512];
  float s = v0 + v1 + v2;
  float s2 = v0 * v0 + v1 * v1 + v2 * v2;
  #pragma unroll
  for (int off = 1; off < 64; off <<= 1){ s += __shfl_xor(s, off); s2 += __shfl_xor(s2, off); }
  __shared__ float red[8];
  int wid = t >> 6, lane = t & 63;
  if (lane == 0){ red[wid] = s; red[4 + wid] = s2; }
  __syncthreads();
  s = red[0] + red[1] + red[2] + red[3];
  s2 = red[4] + red[5] + red[6] + red[7];
  float mean = s * (1.f / 768.f);
  float var = s2 * (1.f / 768.f) - mean * mean;
  float rstd = rsqrtf(var + 1e-5f);
  float o0 = (v0 - mean) * rstd * w[t] + b[t];
  float o1 = (v1 - mean) * rstd * w[t + 256] + b[t + 256];
  float o2 = (v2 - mean) * rstd * w[t + 512] + b[t + 512];
  xln[(size_t)row * 768 + t]       = o0;
  xln[(size_t)row * 768 + t + 256] = o1;
  xln[(size_t)row * 768 + t + 512] = o2;
  float q = o0 * o0 + o1 * o1 + o2 * o2;
  #pragma unroll
  for (int off = 1; off < 64; off <<= 1){ q += __shfl_xor(q, off); }
  __syncthreads();
  if (lane == 0) red[wid] = q;
  __syncthreads();
  q = red[0] + red[1] + red[2] + red[3];
  float rs = rsqrtf(q * (1.f / 768.f) + 1e-5f);
  outB[(size_t)row * 768 + t]       = f2bf(o0 * rs * rw[t]);
  outB[(size_t)row * 768 + t + 256] = f2bf(o1 * rs * rw[t + 256]);
  outB[(size_t)row * 768 + t + 512] = f2bf(o2 * rs * rw[t + 512]);
}

// ---------------- LayerNorm (row=768) -> bf16 only ----------------
__global__ __launch_bounds__(256) void ln_kernel(const float* __restrict__ in,
                                                 const float* __restrict__ w,
                                                 const float* __restrict__ b,
                                                 u16* __restrict__ outB){
  int row = blockIdx.x;
  const float* x = in + (size_t)row * 768;
  int t = threadIdx.x;
  float v0 = x[t], v1 = x[t + 256], v2 = x[t + 512];
  float s = v0 + v1 + v2;
  float s2 = v0 * v0 + v1 * v1 + v2 * v2;
  #pragma unroll
  for (int off = 1; off < 64; off <<= 1){ s += __shfl_xor(s, off); s2 += __shfl_xor(s2, off); }
  __shared__ float red[8];
  int wid = t >> 6, lane = t & 63;
  if (lane == 0){ red[wid] = s; red[4 + wid] = s2; }
  __syncthreads();
  s = red[0] + red[1] + red[2] + red[3];
  s2 = red[4] + red[5] + red[6] + red[7];
  float mean = s * (1.f / 768.f);
  float var = s2 * (1.f / 768.f) - mean * mean;
  float rstd = rsqrtf(var + 1e-5f);
  #pragma unroll
  for (int j = 0; j < 3; j++){
    int e = t + j * 256;
    float v = (j == 0) ? v0 : (j == 1) ? v1 : v2;
    outB[(size_t)row * 768 + e] = f2bf((v - mean) * rstd * w[e] + b[e]);
  }
}

// ------- depthwise causal conv K=4 + bias + SiLU -> xi bf16; also silu(z) -> zs bf16 -------
__global__ __launch_bounds__(256) void conv_silu(const u16* __restrict__ xzb,
                                                 const float* __restrict__ cw,
                                                 const float* __restrict__ cb,
                                                 u16* __restrict__ xi,
                                                 u16* __restrict__ zs){
  int row = blockIdx.x;            // 0..2047
  int b = row >> 10, l = row & 1023;
  for (int e = threadIdx.x; e < 768; e += 256){
    const float* w = cw + (size_t)e * 4;
    float acc = cb[e];
    #pragma unroll
    for (int k = 0; k < 4; k++){
      int ls = l - 3 + k;
      if (ls >= 0) acc += w[k] * bf2f(xzb[((size_t)((b << 10) + ls)) * 1536 + e]);
    }
    float sv = acc / (1.f + __expf(-acc));
    xi[(size_t)row * 768 + e] = f2bf(sv);
    float z = bf2f(xzb[(size_t)row * 1536 + 768 + e]);
    zs[(size_t)row * 768 + e] = f2bf(z / (1.f + __expf(-z)));
  }
}

// ---------------- selective scan, chunk=32: pass 1 (chunk summaries, a/b interleaved) ------
__global__ __launch_bounds__(256) void scan_pass1(const float* __restrict__ delta,
                                                  const u16* __restrict__ xi,
                                                  const float* __restrict__ bc,
                                                  const float* __restrict__ A_log,
                                                  float2* __restrict__ ab){
  int bid = blockIdx.x;                       // 192 = b(2) * c(32) * eg(3)
  int eg = bid % 3; int c = (bid / 3) & 31; int b = bid / 96;
  int e = eg * 256 + threadIdx.x;
  float A[16], a[16], s[16];
  const float* al = A_log + (size_t)e * 16;
  #pragma unroll
  for (int n = 0; n < 16; n++){ A[n] = -__expf(al[n]); a[n] = 1.f; s[n] = 0.f; }
  for (int ll = 0; ll < 32; ll++){
    int row = b * 1024 + c * 32 + ll;
    float dlt = delta[(size_t)row * 768 + e];
    float xiv = bf2f(xi[(size_t)row * 768 + e]);
    float du = dlt * xiv;
    const float* bm = bc + (size_t)row * 32;
    #pragma unroll
    for (int n = 0; n < 16; n++){
      float dA = __expf(dlt * A[n]);
      s[n] = dA * s[n] + du * bm[n];
      a[n] *= dA;
    }
  }
  size_t base = (((size_t)(b * 32 + c) * 768) + e) * 16;
  #pragma unroll
  for (int n = 0; n < 16; n++){ ab[base + n] = make_float2(a[n], s[n]); }
}

// ---------------- scan pass 2: combine 32 chunk summaries ----------------
__global__ __launch_bounds__(128) void scan_pass2(const float2* __restrict__ ab,
                                                  float* __restrict__ h0){
  int idx = blockIdx.x * 128 + threadIdx.x;   // 0..24575 = b*12288 + en
  int b = idx / 12288;
  int en = idx - b * 12288;
  float h = 0.f;
  for (int c = 0; c < 32; c++){
    size_t i = ((size_t)(b * 32 + c) * 12288) + en;
    h0[i] = h;
    float2 v = ab[i];
    h = v.x * h + v.y;
  }
}

// ---------------- scan pass 3: rescan with init state + y epilogue ----------------
__global__ __launch_bounds__(256) void scan_pass3(const float* __restrict__ delta,
                                                  const u16* __restrict__ xi,
                                                  const float* __restrict__ bc,
                                                  const float* __restrict__ A_log,
                                                  const float* __restrict__ h0,
                                                  const float* __restrict__ Dp,
                                                  const u16* __restrict__ zs,
                                                  u16* __restrict__ y){
  int bid = blockIdx.x;
  int eg = bid % 3; int c = (bid / 3) & 31; int b = bid / 96;
  int e = eg * 256 + threadIdx.x;
  float A[16], s[16];
  const float* al = A_log + (size_t)e * 16;
  #pragma unroll
  for (int n = 0; n < 16; n++) A[n] = -__expf(al[n]);
  size_t base = (((size_t)(b * 32 + c) * 768) + e) * 16;
  #pragma unroll
  for (int n = 0; n < 16; n++) s[n] = h0[base + n];
  float dp = Dp[e];
  for (int ll = 0; ll < 32; ll++){
    int row = b * 1024 + c * 32 + ll;
    float dlt = delta[(size_t)row * 768 + e];
    float xiv = bf2f(xi[(size_t)row * 768 + e]);
    float du = dlt * xiv;
    const float* bm = bc + (size_t)row * 32;
    const float* cm = bm + 16;
    float acc = 0.f;
    #pragma unroll
    for (int n = 0; n < 16; n++){
      float dA = __expf(dlt * A[n]);
      s[n] = dA * s[n] + du * bm[n];
      acc += s[n] * cm[n];
    }
    float yv = acc + dp * xiv;
    yv *= bf2f(zs[(size_t)row * 768 + e]);
    y[(size_t)row * 768 + e] = f2bf(yv);
  }
}

// ---------------- bf16 MFMA GEMM, templated tile TSxTS, BK=64, deep pipeline ----------
// TS=64 : 4 waves x 32x32, 4 LDS bufs (64KB) depth-3 -> 2 blocks/CU, latency cover ~1150cyc
// TS=128: 4 waves x 64x64, 3 LDS bufs (96KB) depth-2 -> MFMA:ds_read ~1.2, cover ~1500cyc
// Raw s_barrier + counted vmcnt keeps prefetch in flight across barriers.
// MODE 0: outF = v + bias? + r1? + r2?  (+ optional outB = bf16(result))
// MODE 1: outB = bf16(relu(v + bias))
// MODE 2: col<768 -> dl = softplus(v+dtb); col<800 -> bco = v; else drop
// MODE 3: outB = bf16(v)
template<int MODE, int TS>
__global__ __launch_bounds__(256, 2) void gemmT(
    const u16* __restrict__ A, const u16* __restrict__ Bw, int N, int Kd,
    float* __restrict__ outF, u16* __restrict__ outB,
    const float* __restrict__ bias, const float* __restrict__ r1,
    const float* __restrict__ r2,
    float* __restrict__ dl, float* __restrict__ bco, const float* __restrict__ dtb){
  constexpr int NBUF = (TS == 64) ? 4 : 3;
  constexpr int DEPTH = NBUF - 1;
  constexpr int MI = TS / 32;                 // frag repeats per wave
  __shared__ u16 sm[NBUF][2 * TS * 64];
  const int tid = threadIdx.x;
  const int wid = tid >> 6, lane = tid & 63;
  const int lhi = lane >> 4, llo = lane & 15;
  const int wm = (wid >> 1) * (TS / 2), wn = (wid & 1) * (TS / 2);
  int nwg = (int)(gridDim.x * gridDim.y);
  int orig = (int)(blockIdx.y * gridDim.x + blockIdx.x);
  int wg = (orig & 7) * (nwg >> 3) + (orig >> 3);    // XCD-contiguous chunks
  int gx = (int)gridDim.x;
  int bx = wg % gx, by = wg / gx;
  const int m0 = bx * TS, n0 = by * TS;
  const int nk = Kd >> 6;
  f32x4 acc[MI][MI] = {};

  auto stage = [&](int buf, int kt){
    const u16* Ab = A + (size_t)m0 * Kd + kt * 64;
    const u16* Bb = Bw + (size_t)n0 * Kd + kt * 64;
    u16* basep = &sm[buf][0];
    #pragma unroll
    for (int j = 0; j < TS / 32; j++){
      int sl = j * 256 + tid;
      int row = sl >> 3;
      int ch = (sl & 7) ^ (row & 7);
      __builtin_amdgcn_global_load_lds(
          (const __attribute__((address_space(1))) void*)(Ab + (size_t)row * Kd + ch * 8),
          (__attribute__((address_space(3))) void*)(basep + sl * 8), 16, 0, 0);
    }
    #pragma unroll
    for (int j = 0; j < TS / 32; j++){
      int sl = j * 256 + tid;
      int row = sl >> 3;
      int ch = (sl & 7) ^ (row & 7);
      __builtin_amdgcn_global_load_lds(
          (const __attribute__((address_space(1))) void*)(Bb + (size_t)row * Kd + ch * 8),
          (__attribute__((address_space(3))) void*)(basep + TS * 64 + sl * 8), 16, 0, 0);
    }
  };

  #pragma unroll
  for (int t = 0; t < DEPTH; t++) stage(t, t);   // nk >= 8 always
  for (int kt = 0; kt < nk; ++kt){
    if constexpr (TS == 64){
      if (kt + 2 < nk)      asm volatile("s_waitcnt vmcnt(8)" ::: "memory");
      else if (kt + 1 < nk) asm volatile("s_waitcnt vmcnt(4)" ::: "memory");
      else                  asm volatile("s_waitcnt vmcnt(0)" ::: "memory");
    } else {
      if (kt + 1 < nk)      asm volatile("s_waitcnt vmcnt(8)" ::: "memory");
      else                  asm volatile("s_waitcnt vmcnt(0)" ::: "memory");
    }
    __builtin_amdgcn_s_barrier();          // raw barrier: no implicit vmcnt drain
    __builtin_amdgcn_sched_barrier(0);
    if (kt + DEPTH < nk) stage((kt + DEPTH) % NBUF, kt + DEPTH);
    const u16* Asb = &sm[kt % NBUF][0];
    const u16* Bsb = &sm[kt % NBUF][TS * 64];
    short8 af[MI][2], bfr[MI][2];
    #pragma unroll
    for (int mi = 0; mi < MI; mi++){
      int row = wm + mi * 16 + llo;
      const u16* rp = Asb + row * 64;
      #pragma unroll
      for (int s2 = 0; s2 < 2; s2++){
        int ch = (s2 * 4 + lhi) ^ (row & 7);
        af[mi][s2] = *(const short8*)(rp + ch * 8);
      }
    }
    #pragma unroll
    for (int ni = 0; ni < MI; ni++){
      int row = wn + ni * 16 + llo;
      const u16* rp = Bsb + row * 64;
      #pragma unroll
      for (int s2 = 0; s2 < 2; s2++){
        int ch = (s2 * 4 + lhi) ^ (row & 7);
        bfr[ni][s2] = *(const short8*)(rp + ch * 8);
      }
    }
    #pragma unroll
    for (int s2 = 0; s2 < 2; s2++)
      #pragma unroll
      for (int mi = 0; mi < MI; mi++)
        #pragma unroll
        for (int ni = 0; ni < MI; ni++)
          acc[mi][ni] = __builtin_amdgcn_mfma_f32_16x16x32_bf16(
              af[mi][s2], bfr[ni][s2], acc[mi][ni], 0, 0, 0);
  }
  // epilogue
  #pragma unroll
  for (int mi = 0; mi < MI; mi++){
    #pragma unroll
    for (int ni = 0; ni < MI; ni++){
      int r0 = m0 + wm + mi * 16 + lhi * 4;
      int c = n0 + wn + ni * 16 + llo;
      #pragma unroll
      for (int r = 0; r < 4; r++){
        int rr = r0 + r;
        float v = acc[mi][ni][r];
        if (MODE == 0){
          size_t idx = (size_t)rr * N + c;
          if (bias) v += bias[c];
          if (r1) v += r1[idx];
          if (r2) v += r2[idx];
          outF[idx] = v;
          if (outB) outB[idx] = f2bf(v);
        } else if (MODE == 1){
          size_t idx = (size_t)rr * N + c;
          v += bias[c];
          outB[idx] = f2bf(v > 0.f ? v : 0.f);
        } else if (MODE == 3){
          outB[(size_t)rr * N + c] = f2bf(v);
        } else {
          if (c < 768){
            float tv = v + dtb[c];
            dl[(size_t)rr * 768 + c] = (tv > 20.f) ? tv : log1pf(__expf(tv));
          } else if (c < 800){
            bco[(size_t)rr * 32 + (c - 768)] = v;
          }
        }
      }
    }
  }
}

// ------------------------------------------------------------------
extern "C" void kernel_launch(void* const* d_in, const int* in_sizes, int n_in,
                              void* d_out, int out_size, void* d_ws, size_t ws_size,
                              hipStream_t stream){
  (void)in_sizes; (void)n_in; (void)out_size; (void)ws_size;
  const float* x_f       = (const float*)d_in[0];
  const float* in_proj_w = (const float*)d_in[1];
  const float* in_proj_b = (const float*)d_in[2];
  const float* out_proj_w= (const float*)d_in[3];
  const float* out_proj_b= (const float*)d_in[4];
  const float* ln1_w     = (const float*)d_in[5];
  const float* ln1_b     = (const float*)d_in[6];
  const float* ln2_w     = (const float*)d_in[7];
  const float* ln2_b     = (const float*)d_in[8];
  const float* ffn_w1    = (const float*)d_in[9];
  const float* ffn_b1    = (const float*)d_in[10];
  const float* ffn_w2    = (const float*)d_in[11];
  const float* ffn_b2    = (const float*)d_in[12];
  const float* rms_w     = (const float*)d_in[13];
  const float* m_in_w    = (const float*)d_in[14];
  const float* conv_w    = (const float*)d_in[15];
  const float* conv_b    = (const float*)d_in[16];
  const float* xproj_w   = (const float*)d_in[17];
  const float* dt_w      = (const float*)d_in[18];
  const float* dt_b      = (const float*)d_in[19];
  const float* A_log     = (const float*)d_in[20];
  const float* Dp        = (const float*)d_in[21];
  const float* m_out_w   = (const float*)d_in[22];

  char* ws = (char*)d_ws;
  size_t off = 0;
  auto alloc = [&](size_t bytes) -> char* {
    char* p = ws + off;
    off += (bytes + 255) & ~(size_t)255;
    return p;
  };
  u16* wb_inp  = (u16*)alloc((size_t)768 * 512 * 2);
  u16* wb_outp = (u16*)alloc((size_t)512 * 768 * 2);
  u16* wb_min  = (u16*)alloc((size_t)4 * 1536 * 768 * 2);
  u16* wb_mout = (u16*)alloc((size_t)4 * 768 * 768 * 2);
  u16* wb_f1   = (u16*)alloc((size_t)4 * 3072 * 768 * 2);
  u16* wb_f2   = (u16*)alloc((size_t)4 * 768 * 3072 * 2);
  u16* wb_dbc  = (u16*)alloc((size_t)4 * 896 * 768 * 2);
  u16* xbf     = (u16*)alloc((size_t)2048 * 512 * 2);
  float* hA    = (float*)alloc((size_t)2048 * 768 * 4);
  float* hB    = (float*)alloc((size_t)2048 * 768 * 4);
  float* xln   = (float*)alloc((size_t)2048 * 768 * 4);
  u16* xnbf    = (u16*)alloc((size_t)2048 * 768 * 2);
  u16* xzb     = (u16*)alloc((size_t)2048 * 1536 * 2);
  u16* xibf    = (u16*)alloc((size_t)2048 * 768 * 2);
  u16* zsbf    = (u16*)alloc((size_t)2048 * 768 * 2);
  float* dltb  = (float*)alloc((size_t)2048 * 768 * 4);
  float* bcb   = (float*)alloc((size_t)2048 * 32 * 4);
  float2* ab   = (float2*)alloc((size_t)2 * 32 * 768 * 16 * 8);
  float* h0    = (float*)alloc((size_t)2 * 32 * 768 * 16 * 4);
  u16* ybf     = (u16*)alloc((size_t)2048 * 768 * 2);
  u16* tbf     = (u16*)alloc((size_t)2048 * 768 * 2);
  u16* f1bf    = (u16*)alloc((size_t)2048 * 3072 * 2);
  u16* hfbf    = (u16*)alloc((size_t)2048 * 768 * 2);

  // fused conversion: 27787264 elems / 8 per thread / 256 = 13568 blocks
  prep_cvt<<<13568, 256, 0, stream>>>(x_f, in_proj_w, out_proj_w, m_in_w,
                                      m_out_w, ffn_w1, ffn_w2,
                                      xbf, wb_inp, wb_outp, wb_min,
                                      wb_mout, wb_f1, wb_f2);
  build_dbc<<<2048, 256, 0, stream>>>(dt_w, xproj_w, wb_dbc);

  auto gemm64 = [&](int mode, const u16* Ain, const u16* Bww, int N, int K,
                    float* oF, u16* oB, const float* bias, const float* rr1,
                    const float* rr2, float* dl, float* bco, const float* dtb){
    dim3 g(32, N / 64), blk(256);
    if (mode == 0)
      gemmT<0,64><<<g, blk, 0, stream>>>(Ain, Bww, N, K, oF, oB, bias, rr1, rr2, dl, bco, dtb);
    else if (mode == 2)
      gemmT<2,64><<<g, blk, 0, stream>>>(Ain, Bww, N, K, oF, oB, bias, rr1, rr2, dl, bco, dtb);
    else
      gemmT<3,64><<<g, blk, 0, stream>>>(Ain, Bww, N, K, oF, oB, bias, rr1, rr2, dl, bco, dtb);
  };

  // h = x @ in_proj_w.T + b
  gemm64(0, xbf, wb_inp, 768, 512, hA, nullptr, in_proj_b, nullptr, nullptr,
         nullptr, nullptr, nullptr);

  for (int i = 0; i < 4; i++){
    ln_rms_kernel<<<2048, 256, 0, stream>>>(hA, ln1_w + i * 768, ln1_b + i * 768,
                                            rms_w + i * 768, xln, xnbf);
    gemm64(3, xnbf, wb_min + (size_t)i * 1536 * 768, 1536, 768, nullptr, xzb,
           nullptr, nullptr, nullptr, nullptr, nullptr, nullptr);
    conv_silu<<<2048, 256, 0, stream>>>(xzb, conv_w + (size_t)i * 768 * 4,
                                        conv_b + i * 768, xibf, zsbf);
    gemm64(2, xibf, wb_dbc + (size_t)i * 896 * 768, 896, 768, nullptr, nullptr,
           nullptr, nullptr, nullptr, dltb, bcb, dt_b + i * 768);
    scan_pass1<<<192, 256, 0, stream>>>(dltb, xibf, bcb,
                                        A_log + (size_t)i * 768 * 16, ab);
    scan_pass2<<<192, 128, 0, stream>>>(ab, h0);
    scan_pass3<<<192, 256, 0, stream>>>(dltb, xibf, bcb,
                                        A_log + (size_t)i * 768 * 16, h0,
                                        Dp + i * 768, zsbf, ybf);
    // h_mid = h + ln1(h) + y @ m_out_w.T
    gemm64(0, ybf, wb_mout + (size_t)i * 768 * 768, 768, 768, hB, nullptr,
           nullptr, hA, xln, nullptr, nullptr, nullptr);
    ln_kernel<<<2048, 256, 0, stream>>>(hB, ln2_w + i * 768, ln2_b + i * 768, tbf);
    // ffn1: 128x128 tile variant (grid 16x24 = 384 blocks)
    {
      dim3 g(16, 3072 / 128), blk(256);
      gemmT<1,128><<<g, blk, 0, stream>>>(tbf, wb_f1 + (size_t)i * 3072 * 768, 3072, 768,
                                          nullptr, f1bf, ffn_b1 + i * 3072, nullptr,
                                          nullptr, nullptr, nullptr, nullptr);
    }
    // last layer: also emit bf16 of h for out_proj (skips a cvt kernel)
    gemm64(0, f1bf, wb_f2 + (size_t)i * 768 * 3072, 768, 3072, hA,
           (i == 3) ? hfbf : nullptr, ffn_b2 + i * 768, hB, nullptr,
           nullptr, nullptr, nullptr);
  }
  gemm64(0, hfbf, wb_outp, 512, 768, (float*)d_out, nullptr, out_proj_b,
         nullptr, nullptr, nullptr, nullptr, nullptr);
}

// Round 7
// 680.830 us; speedup vs baseline: 1.0661x; 1.0525x over previous
//
#include <hip/hip_runtime.h>
#include <stdint.h>

typedef unsigned short u16;
typedef __attribute__((ext_vector_type(8))) short short8;
typedef __attribute__((ext_vector_type(4))) float f32x4;

static __device__ __forceinline__ u16 f2bf(float f){
  unsigned int x = __float_as_uint(f);
  unsigned int r = (x + 0x7FFFu + ((x >> 16) & 1u)) >> 16;
  return (u16)r;
}
static __device__ __forceinline__ float bf2f(u16 u){
  return __uint_as_float(((unsigned int)u) << 16);
}

// ---------------- fused prep: convert 7 f32 arrays -> bf16, 2 float4/thread ----------------
__global__ __launch_bounds__(256) void prep_cvt(
    const float* __restrict__ s0, const float* __restrict__ s1,
    const float* __restrict__ s2, const float* __restrict__ s3,
    const float* __restrict__ s4, const float* __restrict__ s5,
    const float* __restrict__ s6,
    u16* __restrict__ d0, u16* __restrict__ d1, u16* __restrict__ d2,
    u16* __restrict__ d3, u16* __restrict__ d4, u16* __restrict__ d5,
    u16* __restrict__ d6){
  size_t i = ((size_t)blockIdx.x * 256 + threadIdx.x) * 8;
  const float* src; u16* dst; size_t base;
  if      (i <  1048576){ src = s0; dst = d0; base = 0; }
  else if (i <  1441792){ src = s1; dst = d1; base = 1048576; }
  else if (i <  1835008){ src = s2; dst = d2; base = 1441792; }
  else if (i <  6553600){ src = s3; dst = d3; base = 1835008; }
  else if (i <  8912896){ src = s4; dst = d4; base = 6553600; }
  else if (i < 18350080){ src = s5; dst = d5; base = 8912896; }
  else                  { src = s6; dst = d6; base = 18350080; }
  size_t o = i - base;
  #pragma unroll
  for (int p = 0; p < 2; p++){
    float4 v = *reinterpret_cast<const float4*>(src + o + p * 4);
    union { u16 u[4]; unsigned long long ll; } t;
    t.u[0] = f2bf(v.x); t.u[1] = f2bf(v.y); t.u[2] = f2bf(v.z); t.u[3] = f2bf(v.w);
    *reinterpret_cast<unsigned long long*>(dst + o + p * 4) = t.ll;
  }
}

// ---------------- build combined [W_delta ; xproj_BC ; pad] (896 x 768) bf16 per layer ----
__global__ __launch_bounds__(256) void build_dbc(const float* __restrict__ dt_w,
                                                 const float* __restrict__ xproj_w,
                                                 u16* __restrict__ out){
  const int total = 4 * 896 * 768;
  for (int idx = blockIdx.x * 256 + threadIdx.x; idx < total; idx += gridDim.x * 256){
    int l = idx / (896 * 768);
    int rem = idx - l * 896 * 768;
    int row = rem / 768;
    int k = rem - row * 768;
    float v = 0.f;
    if (row < 768){
      const float* dtr = dt_w + ((size_t)l * 768 + row) * 48;
      const float* xp  = xproj_w + (size_t)l * 80 * 768 + k;
      #pragma unroll 8
      for (int j = 0; j < 48; j++) v += dtr[j] * xp[(size_t)j * 768];
    } else if (row < 800){
      v = xproj_w[(size_t)l * 80 * 768 + (size_t)(48 + row - 768) * 768 + k];
    }
    out[idx] = f2bf(v);
  }
}

// ---------------- fused LayerNorm -> xln(f32) + RMSNorm(ln) -> bf16 ----------------
__global__ __launch_bounds__(256) void ln_rms_kernel(const float* __restrict__ in,
                                                     const float* __restrict__ w,
                                                     const float* __restrict__ b,
                                                     const float* __restrict__ rw,
                                                     float* __restrict__ xln,
                                                     u16* __restrict__ outB){
  int row = blockIdx.x;
  const float* x = in + (size_t)row * 768;
  int t = threadIdx.x;
  float v0 = x[t], v1 = x[t + 256], v2 = x[t + 512];
  float s = v0 + v1 + v2;
  float s2 = v0 * v0 + v1 * v1 + v2 * v2;
  #pragma unroll
  for (int off = 1; off < 64; off <<= 1){ s += __shfl_xor(s, off); s2 += __shfl_xor(s2, off); }
  __shared__ float red[8];
  int wid = t >> 6, lane = t & 63;
  if (lane == 0){ red[wid] = s; red[4 + wid] = s2; }
  __syncthreads();
  s = red[0] + red[1] + red[2] + red[3];
  s2 = red[4] + red[5] + red[6] + red[7];
  float mean = s * (1.f / 768.f);
  float var = s2 * (1.f / 768.f) - mean * mean;
  float rstd = rsqrtf(var + 1e-5f);
  float o0 = (v0 - mean) * rstd * w[t] + b[t];
  float o1 = (v1 - mean) * rstd * w[t + 256] + b[t + 256];
  float o2 = (v2 - mean) * rstd * w[t + 512] + b[t + 512];
  xln[(size_t)row * 768 + t]       = o0;
  xln[(size_t)row * 768 + t + 256] = o1;
  xln[(size_t)row * 768 + t + 512] = o2;
  float q = o0 * o0 + o1 * o1 + o2 * o2;
  #pragma unroll
  for (int off = 1; off < 64; off <<= 1){ q += __shfl_xor(q, off); }
  __syncthreads();
  if (lane == 0) red[wid] = q;
  __syncthreads();
  q = red[0] + red[1] + red[2] + red[3];
  float rs = rsqrtf(q * (1.f / 768.f) + 1e-5f);
  outB[(size_t)row * 768 + t]       = f2bf(o0 * rs * rw[t]);
  outB[(size_t)row * 768 + t + 256] = f2bf(o1 * rs * rw[t + 256]);
  outB[(size_t)row * 768 + t + 512] = f2bf(o2 * rs * rw[t + 512]);
}

// ---------------- LayerNorm (row=768) -> bf16 only ----------------
__global__ __launch_bounds__(256) void ln_kernel(const float* __restrict__ in,
                                                 const float* __restrict__ w,
                                                 const float* __restrict__ b,
                                                 u16* __restrict__ outB){
  int row = blockIdx.x;
  const float* x = in + (size_t)row * 768;
  int t = threadIdx.x;
  float v0 = x[t], v1 = x[t + 256], v2 = x[t + 512];
  float s = v0 + v1 + v2;
  float s2 = v0 * v0 + v1 * v1 + v2 * v2;
  #pragma unroll
  for (int off = 1; off < 64; off <<= 1){ s += __shfl_xor(s, off); s2 += __shfl_xor(s2, off); }
  __shared__ float red[8];
  int wid = t >> 6, lane = t & 63;
  if (lane == 0){ red[wid] = s; red[4 + wid] = s2; }
  __syncthreads();
  s = red[0] + red[1] + red[2] + red[3];
  s2 = red[4] + red[5] + red[6] + red[7];
  float mean = s * (1.f / 768.f);
  float var = s2 * (1.f / 768.f) - mean * mean;
  float rstd = rsqrtf(var + 1e-5f);
  #pragma unroll
  for (int j = 0; j < 3; j++){
    int e = t + j * 256;
    float v = (j == 0) ? v0 : (j == 1) ? v1 : v2;
    outB[(size_t)row * 768 + e] = f2bf((v - mean) * rstd * w[e] + b[e]);
  }
}

// ------- depthwise causal conv K=4 + bias + SiLU -> xi bf16; also silu(z) -> zs bf16 -------
__global__ __launch_bounds__(256) void conv_silu(const u16* __restrict__ xzb,
                                                 const float* __restrict__ cw,
                                                 const float* __restrict__ cb,
                                                 u16* __restrict__ xi,
                                                 u16* __restrict__ zs){
  int row = blockIdx.x;            // 0..2047
  int b = row >> 10, l = row & 1023;
  for (int e = threadIdx.x; e < 768; e += 256){
    const float* w = cw + (size_t)e * 4;
    float acc = cb[e];
    #pragma unroll
    for (int k = 0; k < 4; k++){
      int ls = l - 3 + k;
      if (ls >= 0) acc += w[k] * bf2f(xzb[((size_t)((b << 10) + ls)) * 1536 + e]);
    }
    float sv = acc / (1.f + __expf(-acc));
    xi[(size_t)row * 768 + e] = f2bf(sv);
    float z = bf2f(xzb[(size_t)row * 1536 + 768 + e]);
    zs[(size_t)row * 768 + e] = f2bf(z / (1.f + __expf(-z)));
  }
}

// ---------------- selective scan, chunk=32: pass 1 (chunk summaries) ----------------
__global__ __launch_bounds__(256) void scan_pass1(const float* __restrict__ delta,
                                                  const u16* __restrict__ xi,
                                                  const float* __restrict__ bc,
                                                  const float* __restrict__ A_log,
                                                  float2* __restrict__ ab){
  int bid = blockIdx.x;                       // 192 = b(2) * c(32) * eg(3)
  int eg = bid % 3; int c = (bid / 3) & 31; int b = bid / 96;
  int e = eg * 256 + threadIdx.x;
  float A[16], a[16], s[16];
  const float* al = A_log + (size_t)e * 16;
  #pragma unroll
  for (int n = 0; n < 16; n++){ A[n] = -__expf(al[n]); a[n] = 1.f; s[n] = 0.f; }
  for (int ll = 0; ll < 32; ll++){
    int row = b * 1024 + c * 32 + ll;
    float dlt = delta[(size_t)row * 768 + e];
    float xiv = bf2f(xi[(size_t)row * 768 + e]);
    float du = dlt * xiv;
    const float* bm = bc + (size_t)row * 32;
    #pragma unroll
    for (int n = 0; n < 16; n++){
      float dA = __expf(dlt * A[n]);
      s[n] = dA * s[n] + du * bm[n];
      a[n] *= dA;
    }
  }
  size_t base = (((size_t)(b * 32 + c) * 768) + e) * 16;
  #pragma unroll
  for (int n = 0; n < 16; n++){ ab[base + n] = make_float2(a[n], s[n]); }
}

// ---------------- scan pass 2: combine 32 chunk summaries ----------------
__global__ __launch_bounds__(128) void scan_pass2(const float2* __restrict__ ab,
                                                  float* __restrict__ h0){
  int idx = blockIdx.x * 128 + threadIdx.x;   // 0..24575 = b*12288 + en
  int b = idx / 12288;
  int en = idx - b * 12288;
  float h = 0.f;
  for (int c = 0; c < 32; c++){
    size_t i = ((size_t)(b * 32 + c) * 12288) + en;
    h0[i] = h;
    float2 v = ab[i];
    h = v.x * h + v.y;
  }
}

// ---------------- scan pass 3: rescan with init state + y epilogue ----------------
__global__ __launch_bounds__(256) void scan_pass3(const float* __restrict__ delta,
                                                  const u16* __restrict__ xi,
                                                  const float* __restrict__ bc,
                                                  const float* __restrict__ A_log,
                                                  const float* __restrict__ h0,
                                                  const float* __restrict__ Dp,
                                                  const u16* __restrict__ zs,
                                                  u16* __restrict__ y){
  int bid = blockIdx.x;
  int eg = bid % 3; int c = (bid / 3) & 31; int b = bid / 96;
  int e = eg * 256 + threadIdx.x;
  float A[16], s[16];
  const float* al = A_log + (size_t)e * 16;
  #pragma unroll
  for (int n = 0; n < 16; n++) A[n] = -__expf(al[n]);
  size_t base = (((size_t)(b * 32 + c) * 768) + e) * 16;
  #pragma unroll
  for (int n = 0; n < 16; n++) s[n] = h0[base + n];
  float dp = Dp[e];
  for (int ll = 0; ll < 32; ll++){
    int row = b * 1024 + c * 32 + ll;
    float dlt = delta[(size_t)row * 768 + e];
    float xiv = bf2f(xi[(size_t)row * 768 + e]);
    float du = dlt * xiv;
    const float* bm = bc + (size_t)row * 32;
    const float* cm = bm + 16;
    float acc = 0.f;
    #pragma unroll
    for (int n = 0; n < 16; n++){
      float dA = __expf(dlt * A[n]);
      s[n] = dA * s[n] + du * bm[n];
      acc += s[n] * cm[n];
    }
    float yv = acc + dp * xiv;
    yv *= bf2f(zs[(size_t)row * 768 + e]);
    y[(size_t)row * 768 + e] = f2bf(yv);
  }
}

// ---------------- bf16 MFMA GEMM, 64x64 tile, BK=64, 3 bufs depth-2, L2-aware swizzle ----
// XCD k owns M-tiles [4k,4k+4) (A-slice 256 rows x K <= 1.6MB, L2-resident); N sweeps
// within XCD with M fastest (B-tile reused by 4 co-resident M-tiles). Requires
// gridDim.x == 32 (2048/64 M-tiles). Raw s_barrier + counted vmcnt; 3 blocks/CU.
// MODE 0: outF = v + bias? + r1? + r2?  (+ optional outB)  MODE 1: outB=bf16(relu(v+bias))
// MODE 2: col<768 -> dl=softplus(v+dtb); col<800 -> bco=v  MODE 3: outB=bf16(v)
template<int MODE>
__global__ __launch_bounds__(256, 3) void gemm64(
    const u16* __restrict__ A, const u16* __restrict__ Bw, int N, int Kd,
    float* __restrict__ outF, u16* __restrict__ outB,
    const float* __restrict__ bias, const float* __restrict__ r1,
    const float* __restrict__ r2,
    float* __restrict__ dl, float* __restrict__ bco, const float* __restrict__ dtb){
  __shared__ u16 sm[3][2 * 64 * 64];   // 48KB
  const int tid = threadIdx.x;
  const int wid = tid >> 6, lane = tid & 63;
  const int lhi = lane >> 4, llo = lane & 15;
  const int wm = (wid >> 1) * 32, wn = (wid & 1) * 32;
  int orig = (int)(blockIdx.y * gridDim.x + blockIdx.x);
  int xcd = orig & 7;
  int w = orig >> 3;
  int mt = xcd * 4 + (w & 3);          // 4 M-tiles per XCD
  int nt = w >> 2;                     // N sweep within XCD
  const int m0 = mt * 64, n0 = nt * 64;
  const int nk = Kd >> 6;
  f32x4 acc[2][2] = {};

  auto stage = [&](int buf, int kt){
    const u16* Ab = A + (size_t)m0 * Kd + kt * 64;
    const u16* Bb = Bw + (size_t)n0 * Kd + kt * 64;
    u16* basep = &sm[buf][0];
    #pragma unroll
    for (int j = 0; j < 2; j++){
      int sl = j * 256 + tid;
      int row = sl >> 3;
      int ch = (sl & 7) ^ (row & 7);
      __builtin_amdgcn_global_load_lds(
          (const __attribute__((address_space(1))) void*)(Ab + (size_t)row * Kd + ch * 8),
          (__attribute__((address_space(3))) void*)(basep + sl * 8), 16, 0, 0);
    }
    #pragma unroll
    for (int j = 0; j < 2; j++){
      int sl = j * 256 + tid;
      int row = sl >> 3;
      int ch = (sl & 7) ^ (row & 7);
      __builtin_amdgcn_global_load_lds(
          (const __attribute__((address_space(1))) void*)(Bb + (size_t)row * Kd + ch * 8),
          (__attribute__((address_space(3))) void*)(basep + 64 * 64 + sl * 8), 16, 0, 0);
    }
  };

  stage(0, 0);
  stage(1, 1);
  for (int kt = 0; kt < nk; ++kt){
    if (kt + 1 < nk) asm volatile("s_waitcnt vmcnt(4)" ::: "memory"); // tile kt landed
    else             asm volatile("s_waitcnt vmcnt(0)" ::: "memory");
    __builtin_amdgcn_s_barrier();          // raw barrier: no implicit vmcnt drain
    __builtin_amdgcn_sched_barrier(0);
    if (kt + 2 < nk) stage((kt + 2) % 3, kt + 2);
    const u16* Asb = &sm[kt % 3][0];
    const u16* Bsb = &sm[kt % 3][64 * 64];
    short8 af[2][2], bfr[2][2];
    #pragma unroll
    for (int mi = 0; mi < 2; mi++){
      int row = wm + mi * 16 + llo;
      const u16* rp = Asb + row * 64;
      #pragma unroll
      for (int s2 = 0; s2 < 2; s2++){
        int ch = (s2 * 4 + lhi) ^ (row & 7);
        af[mi][s2] = *(const short8*)(rp + ch * 8);
      }
    }
    #pragma unroll
    for (int ni = 0; ni < 2; ni++){
      int row = wn + ni * 16 + llo;
      const u16* rp = Bsb + row * 64;
      #pragma unroll
      for (int s2 = 0; s2 < 2; s2++){
        int ch = (s2 * 4 + lhi) ^ (row & 7);
        bfr[ni][s2] = *(const short8*)(rp + ch * 8);
      }
    }
    __builtin_amdgcn_s_setprio(1);
    #pragma unroll
    for (int s2 = 0; s2 < 2; s2++)
      #pragma unroll
      for (int mi = 0; mi < 2; mi++)
        #pragma unroll
        for (int ni = 0; ni < 2; ni++)
          acc[mi][ni] = __builtin_amdgcn_mfma_f32_16x16x32_bf16(
              af[mi][s2], bfr[ni][s2], acc[mi][ni], 0, 0, 0);
    __builtin_amdgcn_s_setprio(0);
  }
  // epilogue
  #pragma unroll
  for (int mi = 0; mi < 2; mi++){
    #pragma unroll
    for (int ni = 0; ni < 2; ni++){
      int r0 = m0 + wm + mi * 16 + lhi * 4;
      int c = n0 + wn + ni * 16 + llo;
      #pragma unroll
      for (int r = 0; r < 4; r++){
        int rr = r0 + r;
        float v = acc[mi][ni][r];
        if (MODE == 0){
          size_t idx = (size_t)rr * N + c;
          if (bias) v += bias[c];
          if (r1) v += r1[idx];
          if (r2) v += r2[idx];
          outF[idx] = v;
          if (outB) outB[idx] = f2bf(v);
        } else if (MODE == 1){
          size_t idx = (size_t)rr * N + c;
          v += bias[c];
          outB[idx] = f2bf(v > 0.f ? v : 0.f);
        } else if (MODE == 3){
          outB[(size_t)rr * N + c] = f2bf(v);
        } else {
          if (c < 768){
            float tv = v + dtb[c];
            dl[(size_t)rr * 768 + c] = (tv > 20.f) ? tv : log1pf(__expf(tv));
          } else if (c < 800){
            bco[(size_t)rr * 32 + (c - 768)] = v;
          }
        }
      }
    }
  }
}

// ------------------------------------------------------------------
extern "C" void kernel_launch(void* const* d_in, const int* in_sizes, int n_in,
                              void* d_out, int out_size, void* d_ws, size_t ws_size,
                              hipStream_t stream){
  (void)in_sizes; (void)n_in; (void)out_size; (void)ws_size;
  const float* x_f       = (const float*)d_in[0];
  const float* in_proj_w = (const float*)d_in[1];
  const float* in_proj_b = (const float*)d_in[2];
  const float* out_proj_w= (const float*)d_in[3];
  const float* out_proj_b= (const float*)d_in[4];
  const float* ln1_w     = (const float*)d_in[5];
  const float* ln1_b     = (const float*)d_in[6];
  const float* ln2_w     = (const float*)d_in[7];
  const float* ln2_b     = (const float*)d_in[8];
  const float* ffn_w1    = (const float*)d_in[9];
  const float* ffn_b1    = (const float*)d_in[10];
  const float* ffn_w2    = (const float*)d_in[11];
  const float* ffn_b2    = (const float*)d_in[12];
  const float* rms_w     = (const float*)d_in[13];
  const float* m_in_w    = (const float*)d_in[14];
  const float* conv_w    = (const float*)d_in[15];
  const float* conv_b    = (const float*)d_in[16];
  const float* xproj_w   = (const float*)d_in[17];
  const float* dt_w      = (const float*)d_in[18];
  const float* dt_b      = (const float*)d_in[19];
  const float* A_log     = (const float*)d_in[20];
  const float* Dp        = (const float*)d_in[21];
  const float* m_out_w   = (const float*)d_in[22];

  char* ws = (char*)d_ws;
  size_t off = 0;
  auto alloc = [&](size_t bytes) -> char* {
    char* p = ws + off;
    off += (bytes + 255) & ~(size_t)255;
    return p;
  };
  u16* wb_inp  = (u16*)alloc((size_t)768 * 512 * 2);
  u16* wb_outp = (u16*)alloc((size_t)512 * 768 * 2);
  u16* wb_min  = (u16*)alloc((size_t)4 * 1536 * 768 * 2);
  u16* wb_mout = (u16*)alloc((size_t)4 * 768 * 768 * 2);
  u16* wb_f1   = (u16*)alloc((size_t)4 * 3072 * 768 * 2);
  u16* wb_f2   = (u16*)alloc((size_t)4 * 768 * 3072 * 2);
  u16* wb_dbc  = (u16*)alloc((size_t)4 * 896 * 768 * 2);
  u16* xbf     = (u16*)alloc((size_t)2048 * 512 * 2);
  float* hA    = (float*)alloc((size_t)2048 * 768 * 4);
  float* hB    = (float*)alloc((size_t)2048 * 768 * 4);
  float* xln   = (float*)alloc((size_t)2048 * 768 * 4);
  u16* xnbf    = (u16*)alloc((size_t)2048 * 768 * 2);
  u16* xzb     = (u16*)alloc((size_t)2048 * 1536 * 2);
  u16* xibf    = (u16*)alloc((size_t)2048 * 768 * 2);
  u16* zsbf    = (u16*)alloc((size_t)2048 * 768 * 2);
  float* dltb  = (float*)alloc((size_t)2048 * 768 * 4);
  float* bcb   = (float*)alloc((size_t)2048 * 32 * 4);
  float2* ab   = (float2*)alloc((size_t)2 * 32 * 768 * 16 * 8);
  float* h0    = (float*)alloc((size_t)2 * 32 * 768 * 16 * 4);
  u16* ybf     = (u16*)alloc((size_t)2048 * 768 * 2);
  u16* tbf     = (u16*)alloc((size_t)2048 * 768 * 2);
  u16* f1bf    = (u16*)alloc((size_t)2048 * 3072 * 2);
  u16* hfbf    = (u16*)alloc((size_t)2048 * 768 * 2);

  prep_cvt<<<13568, 256, 0, stream>>>(x_f, in_proj_w, out_proj_w, m_in_w,
                                      m_out_w, ffn_w1, ffn_w2,
                                      xbf, wb_inp, wb_outp, wb_min,
                                      wb_mout, wb_f1, wb_f2);
  build_dbc<<<2048, 256, 0, stream>>>(dt_w, xproj_w, wb_dbc);

  auto gemm = [&](int mode, const u16* Ain, const u16* Bww, int N, int K,
                  float* oF, u16* oB, const float* bias, const float* rr1,
                  const float* rr2, float* dl, float* bco, const float* dtb){
    dim3 g(32, N / 64), blk(256);
    if (mode == 0)
      gemm64<0><<<g, blk, 0, stream>>>(Ain, Bww, N, K, oF, oB, bias, rr1, rr2, dl, bco, dtb);
    else if (mode == 1)
      gemm64<1><<<g, blk, 0, stream>>>(Ain, Bww, N, K, oF, oB, bias, rr1, rr2, dl, bco, dtb);
    else if (mode == 2)
      gemm64<2><<<g, blk, 0, stream>>>(Ain, Bww, N, K, oF, oB, bias, rr1, rr2, dl, bco, dtb);
    else
      gemm64<3><<<g, blk, 0, stream>>>(Ain, Bww, N, K, oF, oB, bias, rr1, rr2, dl, bco, dtb);
  };

  // h = x @ in_proj_w.T + b
  gemm(0, xbf, wb_inp, 768, 512, hA, nullptr, in_proj_b, nullptr, nullptr,
       nullptr, nullptr, nullptr);

  for (int i = 0; i < 4; i++){
    ln_rms_kernel<<<2048, 256, 0, stream>>>(hA, ln1_w + i * 768, ln1_b + i * 768,
                                            rms_w + i * 768, xln, xnbf);
    gemm(3, xnbf, wb_min + (size_t)i * 1536 * 768, 1536, 768, nullptr, xzb,
         nullptr, nullptr, nullptr, nullptr, nullptr, nullptr);
    conv_silu<<<2048, 256, 0, stream>>>(xzb, conv_w + (size_t)i * 768 * 4,
                                        conv_b + i * 768, xibf, zsbf);
    gemm(2, xibf, wb_dbc + (size_t)i * 896 * 768, 896, 768, nullptr, nullptr,
         nullptr, nullptr, nullptr, dltb, bcb, dt_b + i * 768);
    scan_pass1<<<192, 256, 0, stream>>>(dltb, xibf, bcb,
                                        A_log + (size_t)i * 768 * 16, ab);
    scan_pass2<<<192, 128, 0, stream>>>(ab, h0);
    scan_pass3<<<192, 256, 0, stream>>>(dltb, xibf, bcb,
                                        A_log + (size_t)i * 768 * 16, h0,
                                        Dp + i * 768, zsbf, ybf);
    // h_mid = h + ln1(h) + y @ m_out_w.T
    gemm(0, ybf, wb_mout + (size_t)i * 768 * 768, 768, 768, hB, nullptr,
         nullptr, hA, xln, nullptr, nullptr, nullptr);
    ln_kernel<<<2048, 256, 0, stream>>>(hB, ln2_w + i * 768, ln2_b + i * 768, tbf);
    gemm(1, tbf, wb_f1 + (size_t)i * 3072 * 768, 3072, 768, nullptr, f1bf,
         ffn_b1 + i * 3072, nullptr, nullptr, nullptr, nullptr, nullptr);
    gemm(0, f1bf, wb_f2 + (size_t)i * 768 * 3072, 768, 3072, hA,
         (i == 3) ? hfbf : nullptr, ffn_b2 + i * 768, hB, nullptr,
         nullptr, nullptr, nullptr);
  }
  gemm(0, hfbf, wb_outp, 512, 768, (float*)d_out, nullptr, out_proj_b,
       nullptr, nullptr, nullptr, nullptr, nullptr);
}